// Round 2
// baseline (3452.320 us; speedup 1.0000x reference)
//
#include <hip/hip_runtime.h>

// SRU stacked RNN, MI355X persistent-pipeline design. Round 4.
// Changes vs round 3 (3136 us):
//  1. Wave split (4 K-quarters x 2 row-halves) -> (2 K-halves x 4 row-groups).
//     kh0 = input part (finishers), kh1 = h part. One LDS partial per output
//     instead of 3 -> red[] is 8 KB/buffer -> DOUBLE-BUFFERED red + a single
//     __syncthreads() per step (was 2). Finisher tail (act+store) is spread
//     over 4 waves (was 2), halving the serial tail.
//  2. Coalesced h-stores: stage 16x16 f16 tile in LDS, transpose, one 16B
//     global_store_dwordx4 sc0 sc1 per lane (was 8 scattered 2B stores/lane).
//     vmcnt(0) drain now waits on wide stores; no 2B RMW storm at L3.
//  3. Per-(rh,mh) flags: each finisher wave publishes its own row-group right
//     after its own drain; consumer waves poll exactly the rows they read.
//  4. Poll slack-tracking (+16/+4/+1 __all probes) lets input-part waves skip
//     the ~700cy poll round trip when the upstream layer runs ahead.
//  5. out/h_final stores moved after the flag publish (off critical path).
// Requires ws_size >= ~161 MB (ring 128 MB + ctrl 4 KB + x16 32 MB).

typedef _Float16 f16;
typedef _Float16 f16x8 __attribute__((ext_vector_type(8)));
typedef _Float16 f16x4 __attribute__((ext_vector_type(4)));
typedef float    floatx4 __attribute__((ext_vector_type(4)));

#define T_ 256
#define B_ 64
#define L_ 4
#define H_ 1024
#define IN_ 1024
#define K_ 2048

#define PANEL (B_*H_)                             // 65536 f16 per (layer,t) slot
#define RING_BYTES ((size_t)L_*T_*PANEL*2)        // 128 MB, slots never recycled
#define CTRL_OFF   RING_BYTES
#define CTRL_BYTES 4096                           // 16 flag lines x 256B
#define X16_OFF    (CTRL_OFF + 65536)             // 64KB-aligned tail

// ---------------- x fp32 -> fp16 ----------------
__global__ void convert_x_kernel(const float* __restrict__ x, f16* __restrict__ x16) {
  const int nvec = (T_*B_*IN_)/4;
  const int stride = gridDim.x*blockDim.x;
  for (int v = blockIdx.x*blockDim.x + threadIdx.x; v < nvec; v += stride) {
    floatx4 in = ((const floatx4*)x)[v];
    f16x4 o; o.x = (f16)in.x; o.y = (f16)in.y; o.z = (f16)in.z; o.w = (f16)in.w;
    ((f16x4*)x16)[v] = o;
  }
}

// Gather-poll one 64-slot flag line; returns the proven floor (tgt + slack).
// Slack probes reuse the already-gathered vector: no extra memory traffic.
__device__ __forceinline__ unsigned poll_line(const unsigned int* line, unsigned tgt) {
  const unsigned int* p = line + (threadIdx.x & 63);
  for (;;) {
    unsigned v = __hip_atomic_load(p, __ATOMIC_RELAXED, __HIP_MEMORY_SCOPE_SYSTEM);
    if (__all((int)(v >= tgt))) {
      unsigned a = tgt;
      if      (__all((int)(v >= tgt + 16))) a = tgt + 16;
      else if (__all((int)(v >= tgt + 4)))  a = tgt + 4;
      else if (__all((int)(v >= tgt + 1)))  a = tgt + 1;
      asm volatile("" ::: "memory");   // keep dependent A-loads below the poll
      return a;
    }
    __builtin_amdgcn_s_sleep(2);
  }
}

// ---------------- main persistent kernel ----------------
__global__ __launch_bounds__(512, 2) void sru_main(
    const float* __restrict__ W,      // [L][2048][2048]
    const float* __restrict__ bias,   // [L][2048]
    const f16*  __restrict__ x16,     // [T][64][1024]
    f16*        __restrict__ ring,    // [L][T][64*1024], write-once slots
    unsigned int* __restrict__ done,  // [L][2rh][2mh][64c] flag slots
    float*      __restrict__ out)     // [T*64*1024 outputs][L*64*1024 h_final]
{
  __shared__ f16 Wt[32][2056];                 // 131584 B
  __shared__ float red[2][4][2][64][4];        // 16384 B: [buf][grp][nh][lane][4]
  __shared__ f16 hst[64][24];                  // 3072 B: store-transpose staging

  const int bid  = blockIdx.x;
  const int l    = bid >> 6;
  const int c    = bid & 63;
  const int n0   = c*16;
  const int tid  = threadIdx.x;
  const int lane = tid & 63;
  const int quad = lane >> 4;
  const int lc   = lane & 15;
  const int w    = tid >> 6;         // wave 0..7
  const int kh   = w & 1;            // 0 = input K-half (finisher), 1 = h K-half
  const int mh   = (w >> 1) & 1;
  const int rh   = w >> 2;
  const int R    = rh*32 + mh*16;    // this wave's 16-row group
  const int grp  = rh*2 + mh;        // 0..3

  // ---- phase 0: stage W slice into LDS ----
  {
    const int jj = tid & 15;
    const int k0 = tid >> 4;
    const float* Wl = W + (size_t)l*K_*2048;
    for (int i = 0; i < 64; ++i) {
      int k = k0 + i*32;
      Wt[jj][k]      = (f16)Wl[(size_t)k*2048 + n0 + jj];
      Wt[16 + jj][k] = (f16)Wl[(size_t)k*2048 + 1024 + n0 + jj];
    }
  }
  const float bl = bias[l*2048 + n0 + lc];
  const float bf = bias[l*2048 + 1024 + n0 + lc];
  __syncthreads();

  floatx4 hreg = 0.f;                // finisher waves: 4 h values per lane

  unsigned int* lineL = done + ((l*4 + grp) << 6);
  unsigned int* lineP = (l > 0) ? done + (((l-1)*4 + grp) << 6) : (unsigned int*)0;
  unsigned avail = 0;                // proven floor of the polled line

  // B-operand pointers: cols n0+lc (learn) and 1024+n0+lc (forget), K-half kh.
  const f16* bpL = &Wt[lc][kh*1024 + quad*8];
  const f16* bpF = &Wt[16 + lc][kh*1024 + quad*8];

  for (int t = 0; t < T_; ++t) {
    // --- per-wave waits ---
    if (kh == 0) {
      if (l > 0 && avail < (unsigned)(t+1)) avail = poll_line(lineP, (unsigned)(t+1));
    } else {
      if (t > 0) poll_line(lineL, (unsigned)t);   // own layer never runs ahead
    }

    floatx4 accLa = 0.f, accLb = 0.f, accFa = 0.f, accFb = 0.f;

    if (!(kh == 1 && t == 0)) {        // t==0 h-part is exactly zero: skip
      const f16* Abase;
      if (kh == 1)      Abase = ring + (size_t)(l*T_ + (t-1))*PANEL;
      else if (l == 0)  Abase = x16 + (size_t)t*PANEL;
      else              Abase = ring + (size_t)((l-1)*T_ + t)*PANEL;
      const f16* ap = Abase + (size_t)(R + lc)*H_ + quad*8;

      #pragma unroll
      for (int g = 0; g < 4; ++g) {
        floatx4 ar[8];
        #pragma unroll
        for (int j = 0; j < 8; ++j)
          ar[j] = *(const floatx4*)(ap + (g*8 + j)*32);
        #pragma unroll
        for (int j = 0; j < 8; ++j) {
          f16x8 av = __builtin_bit_cast(f16x8, ar[j]);
          f16x8 bL = *(const f16x8*)(bpL + (g*8 + j)*32);
          f16x8 bF = *(const f16x8*)(bpF + (g*8 + j)*32);
          if (g & 1) {
            accLb = __builtin_amdgcn_mfma_f32_16x16x32_f16(av, bL, accLb, 0,0,0);
            accFb = __builtin_amdgcn_mfma_f32_16x16x32_f16(av, bF, accFb, 0,0,0);
          } else {
            accLa = __builtin_amdgcn_mfma_f32_16x16x32_f16(av, bL, accLa, 0,0,0);
            accFa = __builtin_amdgcn_mfma_f32_16x16x32_f16(av, bF, accFa, 0,0,0);
          }
        }
      }
    }

    if (kh == 1) {                      // h-part: publish partial to red[t&1]
      *(floatx4*)&red[t&1][grp][0][lane][0] = accLa + accLb;
      *(floatx4*)&red[t&1][grp][1][lane][0] = accFa + accFb;
    }
    __syncthreads();                    // the ONLY barrier per step

    if (kh == 0) {
      floatx4 zL = accLa + accLb + *(const floatx4*)&red[t&1][grp][0][lane][0];
      floatx4 zF = accFa + accFb + *(const floatx4*)&red[t&1][grp][1][lane][0];
      f16* ringw = ring + (size_t)(l*T_ + t)*PANEL;

      #pragma unroll
      for (int r = 0; r < 4; ++r) {
        float zl = zL[r] + bl;
        float zf = zF[r] + bf;
        float fg = 1.0f/(1.0f + __expf(-zf));
        float th = 1.0f - 2.0f/(__expf(2.0f*zl) + 1.0f);
        float hn = fg*hreg[r] + (1.0f - fg)*th;
        hreg[r] = hn;
        hst[R + quad*4 + r][lc] = (f16)hn;   // stage for wide store
      }
      // same-wave LDS RAW: make the transpose reads wait for the writes
      asm volatile("s_waitcnt lgkmcnt(0)" ::: "memory");
      __builtin_amdgcn_sched_barrier(0);

      if (lane < 32) {                  // 16 rows x 2 halves = 32 x 16B stores
        int srow = R + (lane >> 1);
        int sh   = lane & 1;
        floatx4 hv = *(const floatx4*)&hst[srow][sh*8];
        asm volatile("global_store_dwordx4 %0, %1, off sc0 sc1"
                     :: "v"((void*)(ringw + (size_t)srow*H_ + n0 + sh*8)),
                        "v"(hv) : "memory");
      }
      asm volatile("s_waitcnt vmcnt(0)" ::: "memory");   // drain own wide stores
      if (lane == 0)
        __hip_atomic_store(lineL + c, (unsigned)(t+1),
                           __ATOMIC_RELAXED, __HIP_MEMORY_SCOPE_SYSTEM);

      // off-critical-path outputs (plain cached stores)
      if (l == 3) {
        #pragma unroll
        for (int r = 0; r < 4; ++r)
          out[(size_t)t*PANEL + (size_t)(R + quad*4 + r)*H_ + n0 + lc] = hreg[r];
      }
      if (t == T_ - 1) {
        #pragma unroll
        for (int r = 0; r < 4; ++r)
          out[(size_t)T_*PANEL + (size_t)l*PANEL + (size_t)(R + quad*4 + r)*H_ + n0 + lc] = hreg[r];
      }
    }
    // No second barrier: red is double-buffered (writers use red[(t+1)&1] next
    // iter; they can only reach red[t&1] again after the NEXT barrier, by which
    // time this iter's readers are done).
  }
}

extern "C" void kernel_launch(void* const* d_in, const int* in_sizes, int n_in,
                              void* d_out, int out_size, void* d_ws, size_t ws_size,
                              hipStream_t stream) {
  (void)in_sizes; (void)n_in; (void)out_size; (void)ws_size;
  const float* x = (const float*)d_in[0];
  const float* W = (const float*)d_in[2];
  const float* b = (const float*)d_in[3];
  float* out = (float*)d_out;

  char* ws = (char*)d_ws;
  f16* ring = (f16*)ws;
  unsigned int* done = (unsigned int*)(ws + CTRL_OFF);
  f16* x16 = (f16*)(ws + X16_OFF);

  hipMemsetAsync(ws + CTRL_OFF, 0, CTRL_BYTES, stream);
  convert_x_kernel<<<1024, 256, 0, stream>>>(x, x16);

  void* args[] = { (void*)&W, (void*)&b, (void*)&x16, (void*)&ring, (void*)&done, (void*)&out };
  hipLaunchCooperativeKernel((const void*)sru_main, dim3(256), dim3(512), args, 0, stream);
}

// Round 3
// 3275.756 us; speedup vs baseline: 1.0539x; 1.0539x over previous
//
#include <hip/hip_runtime.h>

// SRU stacked RNN, MI355X persistent-pipeline design. Round 5.
// Changes vs round 4 (3452 us):
//  1. T2 XOR-swizzle on Wt: Wt[32][2048] (pad dropped), element (row,k) stored
//     at column k ^ ((row&7)<<3). The B ds_read_b128 pattern (16 lanes, same
//     k-range, different rows) was a 4-slot/16-lane pileup -> 1.35e8 conflict
//     cycles (~2060 cy/block-step on the critical h-MFMA chain). Swizzled
//     reads hit all 8 16B-slots evenly (floor-optimal). Read addresses fold
//     into 4 base pointers + compile-time immediates.
//  2. Poll-pressure cut: ~1800 waves were gather-polling flag lines every
//     ~800cy (~300 GB/s of L3 poll traffic, most of FETCH_SIZE) -> loaded-L3
//     latency inflation on the very round trips being polled. Two-phase
//     backoff: one coarse s_sleep (kh1 2048cy / kh0 1024cy) then fine
//     s_sleep(4) polls. ~3-4x fewer poll round trips.
// Requires ws_size >= ~161 MB (ring 128 MB + ctrl 4 KB + x16 32 MB).

typedef _Float16 f16;
typedef _Float16 f16x8 __attribute__((ext_vector_type(8)));
typedef _Float16 f16x4 __attribute__((ext_vector_type(4)));
typedef float    floatx4 __attribute__((ext_vector_type(4)));

#define T_ 256
#define B_ 64
#define L_ 4
#define H_ 1024
#define IN_ 1024
#define K_ 2048

#define PANEL (B_*H_)                             // 65536 f16 per (layer,t) slot
#define RING_BYTES ((size_t)L_*T_*PANEL*2)        // 128 MB, slots never recycled
#define CTRL_OFF   RING_BYTES
#define CTRL_BYTES 4096                           // 16 flag lines x 256B
#define X16_OFF    (CTRL_OFF + 65536)             // 64KB-aligned tail

// ---------------- x fp32 -> fp16 ----------------
__global__ void convert_x_kernel(const float* __restrict__ x, f16* __restrict__ x16) {
  const int nvec = (T_*B_*IN_)/4;
  const int stride = gridDim.x*blockDim.x;
  for (int v = blockIdx.x*blockDim.x + threadIdx.x; v < nvec; v += stride) {
    floatx4 in = ((const floatx4*)x)[v];
    f16x4 o; o.x = (f16)in.x; o.y = (f16)in.y; o.z = (f16)in.z; o.w = (f16)in.w;
    ((f16x4*)x16)[v] = o;
  }
}

// Two-phase gather-poll: immediate check, coarse sleep once, then fine polls.
// SLACK: probe +16/+4/+1 on the already-gathered vector (inter-layer only).
template<int CSLP, int FSLP, bool SLACK>
__device__ __forceinline__ unsigned poll_bk(const unsigned int* line, unsigned tgt) {
  const unsigned int* p = line + (threadIdx.x & 63);
  unsigned v = __hip_atomic_load(p, __ATOMIC_RELAXED, __HIP_MEMORY_SCOPE_SYSTEM);
  if (!__all((int)(v >= tgt))) {
    __builtin_amdgcn_s_sleep(CSLP);        // bulk of the structural gap
    for (;;) {
      v = __hip_atomic_load(p, __ATOMIC_RELAXED, __HIP_MEMORY_SCOPE_SYSTEM);
      if (__all((int)(v >= tgt))) break;
      __builtin_amdgcn_s_sleep(FSLP);      // fine phase: period ~ load latency
    }
  }
  unsigned a = tgt;
  if (SLACK) {
    if      (__all((int)(v >= tgt + 16))) a = tgt + 16;
    else if (__all((int)(v >= tgt + 4)))  a = tgt + 4;
    else if (__all((int)(v >= tgt + 1)))  a = tgt + 1;
  }
  asm volatile("" ::: "memory");   // keep dependent A-loads below the poll
  return a;
}

// ---------------- main persistent kernel ----------------
__global__ __launch_bounds__(512, 2) void sru_main(
    const float* __restrict__ W,      // [L][2048][2048]
    const float* __restrict__ bias,   // [L][2048]
    const f16*  __restrict__ x16,     // [T][64][1024]
    f16*        __restrict__ ring,    // [L][T][64*1024], write-once slots
    unsigned int* __restrict__ done,  // [L][4grp][64c] flag slots
    float*      __restrict__ out)     // [T*64*1024 outputs][L*64*1024 h_final]
{
  __shared__ f16 Wt[32][2048];                 // 131072 B, XOR-swizzled cols
  __shared__ float red[2][4][2][64][4];        // 16384 B: [buf][grp][nh][lane][4]
  __shared__ f16 hst[64][24];                  // 3072 B: store-transpose staging

  const int bid  = blockIdx.x;
  const int l    = bid >> 6;
  const int c    = bid & 63;
  const int n0   = c*16;
  const int tid  = threadIdx.x;
  const int lane = tid & 63;
  const int quad = lane >> 4;
  const int lc   = lane & 15;
  const int w    = tid >> 6;         // wave 0..7
  const int kh   = w & 1;            // 0 = input K-half (finisher), 1 = h K-half
  const int mh   = (w >> 1) & 1;
  const int rh   = w >> 2;
  const int R    = rh*32 + mh*16;    // this wave's 16-row group
  const int grp  = rh*2 + mh;        // 0..3

  // ---- phase 0: stage W slice into LDS (swizzled) ----
  {
    const int jj = tid & 15;
    const int k0 = tid >> 4;                  // 0..31
    const int x0 = (jj & 7) << 3;             // swizzle for rows jj and 16+jj
    const float* Wl = W + (size_t)l*K_*2048;
    for (int i = 0; i < 64; ++i) {
      int k = k0 + i*32;
      int ks = k ^ x0;
      Wt[jj][ks]      = (f16)Wl[(size_t)k*2048 + n0 + jj];
      Wt[16 + jj][ks] = (f16)Wl[(size_t)k*2048 + 1024 + n0 + jj];
    }
  }
  const float bl = bias[l*2048 + n0 + lc];
  const float bf = bias[l*2048 + 1024 + n0 + lc];
  __syncthreads();

  floatx4 hreg = 0.f;                // finisher waves: 4 h values per lane

  unsigned int* lineL = done + ((l*4 + grp) << 6);
  unsigned int* lineP = (l > 0) ? done + (((l-1)*4 + grp) << 6) : (unsigned int*)0;
  unsigned avail = 0;                // proven floor of the upstream line

  // Swizzled B base pointers: logical col = kh*1024 + m*64 + (j&1)*32 + quad*8,
  // physical = logical ^ ((lc&7)<<3). Bits {3,4,5} live in sw0/sw1; kh*1024 and
  // m*64 are swizzle-invariant -> compile-time immediates per unrolled j.
  const int xr  = (lc & 7) << 3;
  const int sw0 = (quad*8) ^ xr;           // even j (col bit5 = 0)
  const int sw1 = (32 + quad*8) ^ xr;      // odd j  (col bit5 = 1)
  const int kb  = kh*1024;
  const f16* bL0 = &Wt[lc][sw0];
  const f16* bL1 = &Wt[lc][sw1];
  const f16* bF0 = &Wt[16 + lc][sw0];
  const f16* bF1 = &Wt[16 + lc][sw1];

  for (int t = 0; t < T_; ++t) {
    // --- per-wave waits ---
    if (kh == 0) {
      if (l > 0 && avail < (unsigned)(t+1))
        avail = poll_bk<16, 4, true>(lineP, (unsigned)(t+1));
    } else {
      if (t > 0) (void)poll_bk<32, 4, false>(lineL, (unsigned)t);
    }

    floatx4 accLa = 0.f, accLb = 0.f, accFa = 0.f, accFb = 0.f;

    if (!(kh == 1 && t == 0)) {        // t==0 h-part is exactly zero: skip
      const f16* Abase;
      if (kh == 1)      Abase = ring + (size_t)(l*T_ + (t-1))*PANEL;
      else if (l == 0)  Abase = x16 + (size_t)t*PANEL;
      else              Abase = ring + (size_t)((l-1)*T_ + t)*PANEL;
      const f16* ap = Abase + (size_t)(R + lc)*H_ + quad*8;

      #pragma unroll
      for (int g = 0; g < 4; ++g) {
        floatx4 ar[8];
        #pragma unroll
        for (int j = 0; j < 8; ++j)
          ar[j] = *(const floatx4*)(ap + (g*8 + j)*32);
        #pragma unroll
        for (int j = 0; j < 8; ++j) {
          const int m = (g*8 + j) >> 1;                   // 0..15
          const f16* pL = (j & 1) ? bL1 : bL0;
          const f16* pF = (j & 1) ? bF1 : bF0;
          f16x8 av = __builtin_bit_cast(f16x8, ar[j]);
          f16x8 bL = *(const f16x8*)(pL + kb + m*64);
          f16x8 bF = *(const f16x8*)(pF + kb + m*64);
          if (g & 1) {
            accLb = __builtin_amdgcn_mfma_f32_16x16x32_f16(av, bL, accLb, 0,0,0);
            accFb = __builtin_amdgcn_mfma_f32_16x16x32_f16(av, bF, accFb, 0,0,0);
          } else {
            accLa = __builtin_amdgcn_mfma_f32_16x16x32_f16(av, bL, accLa, 0,0,0);
            accFa = __builtin_amdgcn_mfma_f32_16x16x32_f16(av, bF, accFa, 0,0,0);
          }
        }
      }
    }

    if (kh == 1) {                      // h-part: publish partial to red[t&1]
      *(floatx4*)&red[t&1][grp][0][lane][0] = accLa + accLb;
      *(floatx4*)&red[t&1][grp][1][lane][0] = accFa + accFb;
    }
    __syncthreads();                    // the ONLY barrier per step

    if (kh == 0) {
      floatx4 zL = accLa + accLb + *(const floatx4*)&red[t&1][grp][0][lane][0];
      floatx4 zF = accFa + accFb + *(const floatx4*)&red[t&1][grp][1][lane][0];
      f16* ringw = ring + (size_t)(l*T_ + t)*PANEL;

      #pragma unroll
      for (int r = 0; r < 4; ++r) {
        float zl = zL[r] + bl;
        float zf = zF[r] + bf;
        float fg = 1.0f/(1.0f + __expf(-zf));
        float th = 1.0f - 2.0f/(__expf(2.0f*zl) + 1.0f);
        float hn = fg*hreg[r] + (1.0f - fg)*th;
        hreg[r] = hn;
        hst[R + quad*4 + r][lc] = (f16)hn;   // stage for wide store
      }
      // same-wave LDS RAW: make the transpose reads wait for the writes
      asm volatile("s_waitcnt lgkmcnt(0)" ::: "memory");
      __builtin_amdgcn_sched_barrier(0);

      if (lane < 32) {                  // 16 rows x 2 halves = 32 x 16B stores
        int srow = R + (lane >> 1);
        int sh   = lane & 1;
        floatx4 hv = *(const floatx4*)&hst[srow][sh*8];
        asm volatile("global_store_dwordx4 %0, %1, off sc0 sc1"
                     :: "v"((void*)(ringw + (size_t)srow*H_ + n0 + sh*8)),
                        "v"(hv) : "memory");
      }
      asm volatile("s_waitcnt vmcnt(0)" ::: "memory");   // drain own wide stores
      if (lane == 0)
        __hip_atomic_store(lineL + c, (unsigned)(t+1),
                           __ATOMIC_RELAXED, __HIP_MEMORY_SCOPE_SYSTEM);

      // off-critical-path outputs (plain cached stores)
      if (l == 3) {
        #pragma unroll
        for (int r = 0; r < 4; ++r)
          out[(size_t)t*PANEL + (size_t)(R + quad*4 + r)*H_ + n0 + lc] = hreg[r];
      }
      if (t == T_ - 1) {
        #pragma unroll
        for (int r = 0; r < 4; ++r)
          out[(size_t)T_*PANEL + (size_t)l*PANEL + (size_t)(R + quad*4 + r)*H_ + n0 + lc] = hreg[r];
      }
    }
    // No second barrier: red is double-buffered (writers touch red[t&1] again
    // only after barrier(t+1), by which time this iter's readers are done).
  }
}

extern "C" void kernel_launch(void* const* d_in, const int* in_sizes, int n_in,
                              void* d_out, int out_size, void* d_ws, size_t ws_size,
                              hipStream_t stream) {
  (void)in_sizes; (void)n_in; (void)out_size; (void)ws_size;
  const float* x = (const float*)d_in[0];
  const float* W = (const float*)d_in[2];
  const float* b = (const float*)d_in[3];
  float* out = (float*)d_out;

  char* ws = (char*)d_ws;
  f16* ring = (f16*)ws;
  unsigned int* done = (unsigned int*)(ws + CTRL_OFF);
  f16* x16 = (f16*)(ws + X16_OFF);

  hipMemsetAsync(ws + CTRL_OFF, 0, CTRL_BYTES, stream);
  convert_x_kernel<<<1024, 256, 0, stream>>>(x, x16);

  void* args[] = { (void*)&W, (void*)&b, (void*)&x16, (void*)&ring, (void*)&done, (void*)&out };
  hipLaunchCooperativeKernel((const void*)sru_main, dim3(256), dim3(512), args, 0, stream);
}